// Round 4
// baseline (33.210 us; speedup 1.0000x reference)
//
#include <hip/hip_runtime.h>

#define NSCALE 16

#if __has_builtin(__builtin_amdgcn_exp2f)
__device__ __forceinline__ float exp2fast(float x) { return __builtin_amdgcn_exp2f(x); }
#else
__device__ __forceinline__ float exp2fast(float x) { return __expf(x * 0.6931471805599453f); }
#endif
#if __has_builtin(__builtin_amdgcn_rsqf)
#define RSQ(x) __builtin_amdgcn_rsqf(x)
#else
#define RSQ(x) rsqrtf(x)
#endif

struct F3 { float x, y, z; };

// Scale groups (s' = global s index + 1; e_{s'/2} = e_{s'}^2):
//  G0 locals {16,12,8,4,2,1,6,3}: exp16, exp12, rest by squaring
//  G1 locals {9,10,11,13,14,15,5,7}: exp 9..15(6x), 5=10^2, 7=14^2
// Pass-2 inverse tables: g-mask 0x7750, sl nibbles 0x0543121027663745.

// Pass 1: one block = (a-tile of 64) x (scale-group G) x (i-chunk cb).
// 8 waves; lane = a. Points broadcast from LDS; per-lane acc[32];
// cross-wave LDS reduce; partial row (64a x 32v) -> P.
template <int G>
__global__ __launch_bounds__(512, 4) void sph_pass1(
    const float* __restrict__ f, const float* __restrict__ coords,
    const float* __restrict__ out_coords, const float* __restrict__ mu,
    float* __restrict__ P, int N, int A, int AT, int CB)
{
    __shared__ __align__(16) float smem[32 * 7 * 64];  // 56 KB; head reused as float4 stage[512]
    float4* s_pts = (float4*)smem;

    const int tid  = threadIdx.x;
    const int lane = tid & 63;
    const int w    = tid >> 6;

    const int bid = blockIdx.x;          // bid = cb*AT + at
    const int at  = bid % AT;
    const int cb  = bid / AT;

    int a = at * 64 + lane; if (a >= A) a = A - 1;
    const float ox = out_coords[3 * a + 0];
    const float oy = out_coords[3 * a + 1];
    const float oz = out_coords[3 * a + 2];

    const float L2E = 1.44269504088896340736f;
    float k0, k1, k2 = 0.f, k3 = 0.f, k4 = 0.f, k5 = 0.f;
    if constexpr (G == 0) {
        k0 = -L2E * mu[15]; k1 = -L2E * mu[11];
    } else {
        k0 = -L2E * mu[8];  k1 = -L2E * mu[9];  k2 = -L2E * mu[10];
        k3 = -L2E * mu[12]; k4 = -L2E * mu[13]; k5 = -L2E * mu[14];
    }

    float acc[32];
#pragma unroll
    for (int v = 0; v < 32; ++v) acc[v] = 0.f;

    const int len  = (N + CB - 1) / CB;
    const int c0   = cb * len;
    const int clen = min(len, N - c0);   // may be <= 0
    const F3* c3 = (const F3*)coords;

    for (int s0 = 0; s0 < clen; s0 += 512) {
        const int seglen = min(512, clen - s0);
        __syncthreads();                 // previous-seg readers done
        if (tid < seglen) {
            const int i = c0 + s0 + tid;
            const F3 p = c3[i];
            s_pts[tid] = make_float4(f[i], p.x, p.y, p.z);
        }
        __syncthreads();
        const int spw = (seglen + 7) >> 3;
        const int t0 = w * spw;
        const int t1 = min(seglen, t0 + spw);
#pragma unroll 4
        for (int t = t0; t < t1; ++t) {
            const float4 p = s_pts[t];   // uniform addr -> LDS broadcast
            const float fi = p.x;
            const float dx = p.y - ox, dy = p.z - oy, dz = p.w - oz;
            const float r2 = fmaf(dx, dx, fmaf(dy, dy, dz * dz));
            const float rinv = RSQ(r2);
            const float r  = r2 * rinv;
            const float fr = fi * rinv;
            const float fx = fr * dx, fy = fr * dy, fz = fr * dz;
            float e[8];
            if constexpr (G == 0) {
                e[0] = exp2fast(k0 * r); e[1] = exp2fast(k1 * r);
                e[2] = e[0] * e[0]; e[3] = e[2] * e[2];
                e[4] = e[3] * e[3]; e[5] = e[4] * e[4];
                e[6] = e[1] * e[1]; e[7] = e[6] * e[6];
            } else {
                e[0] = exp2fast(k0 * r); e[1] = exp2fast(k1 * r);
                e[2] = exp2fast(k2 * r); e[3] = exp2fast(k3 * r);
                e[4] = exp2fast(k4 * r); e[5] = exp2fast(k5 * r);
                e[6] = e[1] * e[1];      e[7] = e[4] * e[4];
            }
#pragma unroll
            for (int s = 0; s < 8; ++s) {
                acc[4 * s + 0] = fmaf(e[s], fi, acc[4 * s + 0]);
                acc[4 * s + 1] = fmaf(e[s], fx, acc[4 * s + 1]);
                acc[4 * s + 2] = fmaf(e[s], fy, acc[4 * s + 2]);
                acc[4 * s + 3] = fmaf(e[s], fz, acc[4 * s + 3]);
            }
        }
    }

    __syncthreads();                     // s_pts no longer needed
    if (w > 0) {
#pragma unroll
        for (int v = 0; v < 32; ++v)
            smem[(v * 7 + (w - 1)) * 64 + lane] = acc[v];  // bank = lane%32: conflict-free
    }
    __syncthreads();
    if (w == 0) {
        float* Pb = P + ((size_t)(cb * 2 + G) * AT + at) * 2048;
#pragma unroll
        for (int v = 0; v < 32; ++v) {
            float s = acc[v];
#pragma unroll
            for (int j = 0; j < 7; ++j) s += smem[(v * 7 + j) * 64 + lane];
            Pb[v * 64 + lane] = s;       // 64-lane coalesced per v
        }
    }
}

// Pass 2: sum CB chunk partials, apply norms, write out[a][64].
__global__ __launch_bounds__(256) void sph_pass2(
    const float* __restrict__ P, const float* __restrict__ r_norms,
    const float* __restrict__ a0, const float* __restrict__ a1,
    float* __restrict__ out, int A, int AT, int CB)
{
    const int tid = blockIdx.x * blockDim.x + threadIdx.x;
    if (tid >= A * 64) return;
    const int a  = tid >> 6;
    const int ov = tid & 63;
    int s, cc;
    if (ov < 16) { s = ov; cc = 0; }
    else { const int q = ov - 16; s = q / 3; cc = q - 3 * s + 1; }
    const int g  = (0x7750 >> s) & 1;
    const int sl = (int)((0x0543121027663745ULL >> (4 * s)) & 15ULL);
    const int v  = 4 * sl + cc;
    const int at = a >> 6, l = a & 63;
    const size_t stride = (size_t)2 * AT * 2048;
    const float* p = P + ((size_t)(g * AT + at)) * 2048 + v * 64 + l;
    float sum = 0.f;
    for (int cb = 0; cb < CB; ++cb) sum += p[(size_t)cb * stride];
    const float scale = r_norms[s] * (cc == 0 ? a0[0] : a1[cc - 1]);
    out[(size_t)a * 64 + ov] = sum * scale;
}

extern "C" void kernel_launch(void* const* d_in, const int* in_sizes, int n_in,
                              void* d_out, int out_size, void* d_ws, size_t ws_size,
                              hipStream_t stream) {
    const float* f          = (const float*)d_in[0];
    const float* coords     = (const float*)d_in[1];
    const float* out_coords = (const float*)d_in[2];
    const float* mu         = (const float*)d_in[3];
    const float* r_norms    = (const float*)d_in[4];
    const float* a_norms_0  = (const float*)d_in[5];
    const float* a_norms_1  = (const float*)d_in[6];
    float* out = (float*)d_out;

    const int N  = in_sizes[0];        // f is [B=1, N]
    const int A  = in_sizes[2] / 3;    // out_coords is [B=1, A, 3]
    const int AT = (A + 63) / 64;

    int CB = 8;                        // i-chunk blocks; partials = CB*2*AT*8KB
    while (CB > 1 && (size_t)CB * 2 * AT * 2048 * sizeof(float) > ws_size) CB >>= 1;

    float* P = (float*)d_ws;
    dim3 grid1(CB * AT);
    sph_pass1<0><<<grid1, 512, 0, stream>>>(f, coords, out_coords, mu, P, N, A, AT, CB);
    sph_pass1<1><<<grid1, 512, 0, stream>>>(f, coords, out_coords, mu, P, N, A, AT, CB);

    const int n2 = A * 64;
    sph_pass2<<<(n2 + 255) / 256, 256, 0, stream>>>(P, r_norms, a_norms_0, a_norms_1,
                                                    out, A, AT, CB);
}